// Round 18
// baseline (309.081 us; speedup 1.0000x reference)
//
#include <hip/hip_runtime.h>

#define NN 100000
#define NE 1600000

#define BSHIFT 9
#define NBKT 256            // compile-time max; used = (N+511)>>9 = 196
#define BCAP 12288          // per-bucket staging capacity (avg 8192, sd ~90)
#define TILE 4096

using half8 = __attribute__((ext_vector_type(8))) _Float16;
using f32x4 = __attribute__((ext_vector_type(4))) float;

// ---- bf16 helpers (round-to-nearest-even, matches numpy/jax cast) ----
__device__ inline unsigned short f2bf(float f) {
    unsigned int u = __float_as_uint(f);
    unsigned int r = (u + 0x7fffu + ((u >> 16) & 1u)) >> 16;
    return (unsigned short)r;
}
__device__ inline float bf2f(unsigned short h) {
    return __uint_as_float(((unsigned int)h) << 16);
}
__device__ inline float bflo(unsigned int v) { return __uint_as_float(v << 16); }
__device__ inline float bfhi(unsigned int v) { return __uint_as_float(v & 0xffff0000u); }
__device__ inline unsigned short f2h(float f) {
    union { _Float16 h; unsigned short u; } c; c.h = (_Float16)f; return c.u;
}

// ---- fill pass 1: bucketize edges by dst>>9 into per-bucket staging ----
__global__ __launch_bounds__(256) void k_bucket(
    const int* __restrict__ src, const int* __restrict__ dst,
    int* __restrict__ gcnt, unsigned* __restrict__ stage, int E) {
    __shared__ unsigned st[TILE];
    __shared__ unsigned char stb[TILE];
    __shared__ int hist4[4 * NBKT];
    __shared__ int hist[NBKT];
    __shared__ int s[NBKT];
    __shared__ int offs[NBKT];
    __shared__ int cursor[NBKT];
    __shared__ int gbase[NBKT];
    int tid = threadIdx.x;
    int wv = tid >> 6;
    int t0 = blockIdx.x * TILE;
    int m = E - t0; if (m > TILE) m = TILE;

    for (int i = tid; i < 4 * NBKT; i += 256) hist4[i] = 0;
    __syncthreads();
    for (int i = tid; i < m; i += 256)
        atomicAdd(&hist4[wv * NBKT + (dst[t0 + i] >> BSHIFT)], 1);
    __syncthreads();
    int h = hist4[tid] + hist4[NBKT + tid] + hist4[2 * NBKT + tid] + hist4[3 * NBKT + tid];
    hist[tid] = h;
    s[tid] = h;
    __syncthreads();
    for (int off = 1; off < NBKT; off <<= 1) {
        int t = (tid >= off) ? s[tid - off] : 0;
        __syncthreads();
        s[tid] += t;
        __syncthreads();
    }
    offs[tid] = s[tid] - hist[tid];
    cursor[tid] = s[tid] - hist[tid];
    gbase[tid] = atomicAdd(&gcnt[tid], hist[tid]);
    __syncthreads();
    for (int i = tid; i < m; i += 256) {
        int d = dst[t0 + i];
        int b = d >> BSHIFT;
        unsigned packed = ((unsigned)src[t0 + i] << BSHIFT) | (unsigned)(d & 511);
        int pos = atomicAdd(&cursor[b], 1);
        st[pos] = packed;
        stb[pos] = (unsigned char)b;
    }
    __syncthreads();
    for (int i = tid; i < m; i += 256) {
        int b = stb[i];
        int idx = gbase[b] + (i - offs[b]);
        if (idx < BCAP) stage[(size_t)b * BCAP + idx] = st[i];
    }
}

// ---- degree histogram + dinv + block-local exclusive scan (merged cnt+scan1) ----
__global__ __launch_bounds__(512) void k_cnt_scan(
    const unsigned* __restrict__ stage, const int* __restrict__ gcnt,
    float* __restrict__ dinv, int* __restrict__ row_ptr, int* __restrict__ bsums, int N) {
    __shared__ int h[512];
    __shared__ int s[512];
    int b = blockIdx.x;
    int tid = threadIdx.x;
    h[tid] = 0;
    __syncthreads();
    int n = gcnt[b]; if (n > BCAP) n = BCAP;
    const unsigned* sg = stage + (size_t)b * BCAP;
    for (int i = tid; i < n; i += 512)
        atomicAdd(&h[sg[i] & 511], 1);
    __syncthreads();
    int v = h[tid];
    int d = (b << BSHIFT) | tid;
    if (d < N) dinv[d] = rsqrtf((float)(v + 1));  // +1 self loop
    s[tid] = v;
    __syncthreads();
    for (int off = 1; off < 512; off <<= 1) {
        int t = (tid >= off) ? s[tid - off] : 0;
        __syncthreads();
        s[tid] += t;
        __syncthreads();
    }
    if (d < N) row_ptr[d] = s[tid] - v;   // block-local exclusive
    if (tid == 511) bsums[b] = s[511];
}

// ---- serial scan of bucket sums + row_ptr[N]=E + pooled zero (one tiny block) ----
__global__ void k_scan2(int* __restrict__ bsums, int nb, int* __restrict__ row_ptr,
                        int N, int E, float* __restrict__ pooled) {
    int tid = threadIdx.x;
    if (tid == 0) {
        int run = 0;
        for (int b = 0; b < nb; ++b) { int t = bsums[b]; bsums[b] = run; run += t; }
        row_ptr[N] = E;
    }
    for (int i = tid; i < 64 * 128; i += blockDim.x) pooled[i] = 0.f;
}

// ---- fill pass 2: finalize row_ptr (+bucket offset) and scatter col via LDS cursors ----
__global__ __launch_bounds__(512) void k_scatter(
    const unsigned* __restrict__ stage, const int* __restrict__ gcnt,
    const int* __restrict__ bsums, int* __restrict__ row_ptr,
    int* __restrict__ col, int N) {
    __shared__ int cur[512];
    int b = blockIdx.x;
    int tid = threadIdx.x;
    int add = bsums[b];
    int d0 = (b << BSHIFT) | tid;
    int base = 0;
    if (d0 < N) {
        base = row_ptr[d0] + add;   // block-local excl + bucket offset = global
        row_ptr[d0] = base;         // finalize for k_agg
    }
    cur[tid] = base;
    __syncthreads();
    int n = gcnt[b]; if (n > BCAP) n = BCAP;
    const unsigned* sg = stage + (size_t)b * BCAP;
    for (int i = tid; i < n; i += 512) {
        unsigned e = sg[i];
        int pos = atomicAdd(&cur[e & 511], 1);
        col[pos] = (int)(e >> BSHIFT);
    }
}

// ---- merged prep: x -> bf16 pre-scaled by dinv (first nconv blocks) +
// ---- W1/W2 f32 -> f16 fragment-major packs (12 tail blocks) ----
__global__ void k_prep(const float* __restrict__ x, const float* __restrict__ dinv,
                       unsigned short* __restrict__ xb,
                       const float* __restrict__ W1, const float* __restrict__ W2,
                       half8* __restrict__ w1p, half8* __restrict__ w2p, int n8) {
    int nconv = (n8 + 255) >> 8;
    int bid = blockIdx.x;
    if (bid < nconv) {
        int i = bid * 256 + threadIdx.x;
        if (i >= n8) return;
        float di = dinv[i >> 3];  // 8 floats/thread, 64 ch/row -> row = i/8
        const float4* p = (const float4*)(x + (size_t)i * 8);
        float4 a = p[0], b = p[1];
        uint4 o;
        o.x = (unsigned)f2bf(di * a.x) | ((unsigned)f2bf(di * a.y) << 16);
        o.y = (unsigned)f2bf(di * a.z) | ((unsigned)f2bf(di * a.w) << 16);
        o.z = (unsigned)f2bf(di * b.x) | ((unsigned)f2bf(di * b.y) << 16);
        o.w = (unsigned)f2bf(di * b.z) | ((unsigned)f2bf(di * b.w) << 16);
        ((uint4*)xb)[i] = o;
    } else {
        int t = (bid - nconv) * 256 + threadIdx.x;
        const float* W; half8* wp; int tt;
        if (t < 1024) { W = W1; wp = w1p; tt = t; }
        else if (t < 3072) { W = W2; wp = w2p; tt = t - 1024; }
        else return;
        int s = tt >> 9;
        int j = (tt >> 6) & 7;
        int l = tt & 63;
        half8 hv;
#pragma unroll
        for (int jj = 0; jj < 8; ++jj)
            hv[jj] = (_Float16)W[(size_t)(32 * s + 8 * (l >> 4) + jj) * 128 + 16 * j + (l & 15)];
        wp[tt] = hv;
    }
}

// ------- aggregation: wave/node; rows pre-scaled by dinv[src]; 8 gathers in
// ------- flight, NO serial tail: ceil(m/8) clamped iterations + overcount fixup -------

template <int C>
__global__ void k_agg(const unsigned short* __restrict__ xb, const int* __restrict__ row_ptr,
                      const int* __restrict__ col, const float* __restrict__ dinv,
                      unsigned short* __restrict__ out, int N) {
    int node = blockIdx.x * (blockDim.x >> 6) + (threadIdx.x >> 6);
    int lane = threadIdx.x & 63;
    if (node >= N) return;
    int beg = row_ptr[node], end = row_ptr[node + 1];
    float di = dinv[node];

    if constexpr (C == 64) {
        float acc = bf2f(xb[(size_t)node * 64 + lane]);  // self (pre-scaled by di)
        for (int base = beg; base < end; base += 64) {
            int m = end - base; if (m > 64) m = 64;
            int sel = (lane < m) ? lane : (m - 1);
            int cl = col[base + sel];                    // lanes >= m hold col[base+m-1]
            int iters = (m + 7) & ~7;
            for (int k = 0; k < iters; k += 8) {
                int c0 = __shfl(cl, k),     c1 = __shfl(cl, k + 1);
                int c2 = __shfl(cl, k + 2), c3 = __shfl(cl, k + 3);
                int c4 = __shfl(cl, k + 4), c5 = __shfl(cl, k + 5);
                int c6 = __shfl(cl, k + 6), c7 = __shfl(cl, k + 7);
                unsigned short v0 = xb[(size_t)c0 * 64 + lane];
                unsigned short v1 = xb[(size_t)c1 * 64 + lane];
                unsigned short v2 = xb[(size_t)c2 * 64 + lane];
                unsigned short v3 = xb[(size_t)c3 * 64 + lane];
                unsigned short v4 = xb[(size_t)c4 * 64 + lane];
                unsigned short v5 = xb[(size_t)c5 * 64 + lane];
                unsigned short v6 = xb[(size_t)c6 * 64 + lane];
                unsigned short v7 = xb[(size_t)c7 * 64 + lane];
                acc += bf2f(v0) + bf2f(v1) + bf2f(v2) + bf2f(v3)
                     + bf2f(v4) + bf2f(v5) + bf2f(v6) + bf2f(v7);
            }
            int extra = iters - m;
            if (extra > 0) {
                int clast = __shfl(cl, m - 1);
                acc -= (float)extra * bf2f(xb[(size_t)clast * 64 + lane]);  // L1-hot
            }
        }
        out[(size_t)node * 64 + lane] = f2h(di * acc);
    } else {
        const unsigned int* xb2 = (const unsigned int*)xb;  // 2 bf16 per uint
        unsigned int sv = xb2[(size_t)node * 64 + lane];
        float ax = bflo(sv), ay = bfhi(sv);                 // self (pre-scaled)
        for (int base = beg; base < end; base += 64) {
            int m = end - base; if (m > 64) m = 64;
            int sel = (lane < m) ? lane : (m - 1);
            int cl = col[base + sel];
            int iters = (m + 7) & ~7;
            for (int k = 0; k < iters; k += 8) {
                int c0 = __shfl(cl, k),     c1 = __shfl(cl, k + 1);
                int c2 = __shfl(cl, k + 2), c3 = __shfl(cl, k + 3);
                int c4 = __shfl(cl, k + 4), c5 = __shfl(cl, k + 5);
                int c6 = __shfl(cl, k + 6), c7 = __shfl(cl, k + 7);
                unsigned int v0 = xb2[(size_t)c0 * 64 + lane];
                unsigned int v1 = xb2[(size_t)c1 * 64 + lane];
                unsigned int v2 = xb2[(size_t)c2 * 64 + lane];
                unsigned int v3 = xb2[(size_t)c3 * 64 + lane];
                unsigned int v4 = xb2[(size_t)c4 * 64 + lane];
                unsigned int v5 = xb2[(size_t)c5 * 64 + lane];
                unsigned int v6 = xb2[(size_t)c6 * 64 + lane];
                unsigned int v7 = xb2[(size_t)c7 * 64 + lane];
                ax += bflo(v0) + bflo(v1) + bflo(v2) + bflo(v3)
                    + bflo(v4) + bflo(v5) + bflo(v6) + bflo(v7);
                ay += bfhi(v0) + bfhi(v1) + bfhi(v2) + bfhi(v3)
                    + bfhi(v4) + bfhi(v5) + bfhi(v6) + bfhi(v7);
            }
            int extra = iters - m;
            if (extra > 0) {
                int clast = __shfl(cl, m - 1);
                unsigned int v = xb2[(size_t)clast * 64 + lane];  // L1-hot
                ax -= (float)extra * bflo(v);
                ay -= (float)extra * bfhi(v);
            }
        }
        ((unsigned int*)out)[(size_t)node * 64 + lane] =
            (unsigned int)f2h(di * ax) | ((unsigned int)f2h(di * ay) << 16);
    }
}

// ------- MFMA GEMM (+bias+relu): out[N,128] = A[N,K](f16) @ W[K,128](f16) -------
// SCALE: multiply output row by dinv[row], write bf16 (layer-1 path).
// POOL:  skip the output write entirely; accumulate rows into pooled[g][c]
//        (block-LDS partial for the block's dominant graph + atomic flush).

template <int K, bool SCALE, bool POOL>
__global__ __launch_bounds__(256) void k_gemm_mfma(
    const unsigned short* __restrict__ A, const half8* __restrict__ wpack,
    const float* __restrict__ bias, const float* __restrict__ dinv,
    unsigned short* __restrict__ outp, const int* __restrict__ batch,
    float* __restrict__ pooled, int N) {
    __shared__ float pl[128];
    int lane = threadIdx.x & 63;
    int wave = threadIdx.x >> 6;
    int row0 = (int)blockIdx.x * 64 + wave * 16;
    int ar = row0 + (lane & 15);
    if (ar >= N) ar = N - 1;
    const _Float16* Ah = (const _Float16*)A;

    int g0 = 0;
    if constexpr (POOL) {
        for (int i = threadIdx.x; i < 128; i += 256) pl[i] = 0.f;
        int br = (int)blockIdx.x * 64;
        if (br > N - 1) br = N - 1;
        g0 = batch[br];
        __syncthreads();
    }

    f32x4 acc[8];
#pragma unroll
    for (int j = 0; j < 8; ++j) acc[j] = (f32x4)(0.f);

#pragma unroll
    for (int s = 0; s < K / 32; ++s) {
        half8 av = *(const half8*)(Ah + (size_t)ar * K + 32 * s + 8 * (lane >> 4));
#pragma unroll
        for (int j = 0; j < 8; ++j) {
            half8 bv = wpack[(s * 8 + j) * 64 + lane];
            acc[j] = __builtin_amdgcn_mfma_f32_16x16x32_f16(av, bv, acc[j], 0, 0, 0);
        }
    }

    int rowb = row0 + (lane >> 4) * 4;
    float dv[4];
#pragma unroll
    for (int r = 0; r < 4; ++r) {
        int rr = rowb + r; if (rr >= N) rr = N - 1;
        dv[r] = SCALE ? dinv[rr] : 1.f;
    }
#pragma unroll
    for (int j = 0; j < 8; ++j) {
        int colc = j * 16 + (lane & 15);
        float b = bias[colc];
#pragma unroll
        for (int r = 0; r < 4; ++r) {
            int rr = rowb + r;
            if (rr < N) {
                float v = fmaxf(acc[j][r] + b, 0.f);
                if constexpr (POOL) {
                    int g = batch[rr];
                    if (g == g0) atomicAdd(&pl[colc], v);
                    else atomicAdd(&pooled[g * 128 + colc], v);  // rare boundary rows
                } else {
                    if constexpr (SCALE) v *= dv[r];
                    outp[(size_t)rr * 128 + colc] = f2bf(v);
                }
            }
        }
    }

    if constexpr (POOL) {
        __syncthreads();
        for (int i = threadIdx.x; i < 128; i += 256) {
            float v = pl[i];
            if (v != 0.f) atomicAdd(&pooled[g0 * 128 + i], v);
        }
    }
}

// final classify; graph counts via binary search on sorted batch (fused in)
__global__ void k_final(const float* __restrict__ pooled, const int* __restrict__ batch,
                        const float* __restrict__ Wc, const float* __restrict__ bc,
                        float* __restrict__ out, int N) {
    __shared__ int cnts[64];
    int tid = threadIdx.x;
    if (tid < 64) {
        int g = tid;
        int lo = 0, hi = N;
        while (lo < hi) { int mid = (lo + hi) >> 1; if (batch[mid] < g) lo = mid + 1; else hi = mid; }
        int start = lo;
        lo = 0; hi = N;
        while (lo < hi) { int mid = (lo + hi) >> 1; if (batch[mid] < g + 1) lo = mid + 1; else hi = mid; }
        cnts[g] = lo - start;
    }
    __syncthreads();
    for (int idx = tid; idx < 64 * 10; idx += 256) {
        int g = idx / 10, c = idx % 10;
        float s = 0.f;
        for (int k = 0; k < 128; ++k) s += pooled[g * 128 + k] * Wc[k * 10 + c];
        float cnt = (float)cnts[g];
        if (cnt < 1.f) cnt = 1.f;
        out[idx] = s / cnt + bc[c];
    }
}

// ---------------- launch ----------------

extern "C" void kernel_launch(void* const* d_in, const int* in_sizes, int n_in,
                              void* d_out, int out_size, void* d_ws, size_t ws_size,
                              hipStream_t stream) {
    const float* x  = (const float*)d_in[0];
    const float* W1 = (const float*)d_in[1];
    const float* b1 = (const float*)d_in[2];
    const float* W2 = (const float*)d_in[3];
    const float* b2 = (const float*)d_in[4];
    const float* Wc = (const float*)d_in[5];
    const float* bc = (const float*)d_in[6];
    const int* ei   = (const int*)d_in[7];
    const int* batch = (const int*)d_in[8];

    const int E = in_sizes[7] / 2;
    const int N = in_sizes[8];
    const int* src = ei;
    const int* dst = ei + E;

    char* p = (char*)d_ws;
    auto alloc = [&](size_t bytes) -> void* {
        void* r = (void*)p;
        p += (bytes + 255) & ~(size_t)255;
        return r;
    };
    float* dinv     = (float*)alloc((size_t)N * 4);
    int*   row_ptr  = (int*)alloc((size_t)(N + 1) * 4);
    int*   bsums    = (int*)alloc(4096);
    int*   col      = (int*)alloc((size_t)E * 4);
    int*   gcnt     = (int*)alloc(NBKT * 4);
    unsigned* stage = (unsigned*)alloc((size_t)NBKT * BCAP * 4);
    unsigned short* xb    = (unsigned short*)alloc((size_t)N * 64 * 2);   // dinv-scaled x
    unsigned short* h1b   = (unsigned short*)alloc((size_t)N * 128 * 2);  // dinv-scaled h1
    unsigned short* aggb1 = (unsigned short*)alloc((size_t)N * 64 * 2);
    unsigned short* aggb2 = (unsigned short*)alloc((size_t)N * 128 * 2);
    half8* w1p      = (half8*)alloc(1024 * 16);
    half8* w2p      = (half8*)alloc(2048 * 16);
    float* pooled   = (float*)alloc(64 * 128 * 4);

    (void)hipMemsetAsync(gcnt, 0, NBKT * 4, stream);

    int nb = (N + 511) / 512;
    int n8 = N * 8;
    int nconv = (n8 + 255) / 256;

    // bucket edges, then derive degrees / CSR entirely bucket-locally
    k_bucket<<<(E + TILE - 1) / TILE, 256, 0, stream>>>(src, dst, gcnt, stage, E);
    k_cnt_scan<<<nb, 512, 0, stream>>>(stage, gcnt, dinv, row_ptr, bsums, N);
    k_scan2<<<1, 256, 0, stream>>>(bsums, nb, row_ptr, N, E, pooled);
    k_scatter<<<nb, 512, 0, stream>>>(stage, gcnt, bsums, row_ptr, col, N);

    // pre-scaled x + weight packs (single merged launch)
    k_prep<<<nconv + 12, 256, 0, stream>>>(x, dinv, xb, W1, W2, w1p, w2p, n8);

    // layer 1: aggregate scaled x -> f16, MFMA transform -> h1b (bf16, dinv-scaled)
    k_agg<64><<<(N + 3) / 4, 256, 0, stream>>>(xb, row_ptr, col, dinv, aggb1, N);
    k_gemm_mfma<64, true, false><<<(N + 63) / 64, 256, 0, stream>>>(
        aggb1, w1p, b1, dinv, h1b, nullptr, nullptr, N);

    // layer 2: aggregate scaled h1 -> f16, MFMA transform fused with mean-pool
    k_agg<128><<<(N + 3) / 4, 256, 0, stream>>>(h1b, row_ptr, col, dinv, aggb2, N);
    k_gemm_mfma<128, false, true><<<(N + 63) / 64, 256, 0, stream>>>(
        aggb2, w2p, b2, nullptr, nullptr, batch, pooled, N);

    // classify
    k_final<<<1, 256, 0, stream>>>(pooled, batch, Wc, bc, (float*)d_out, N);
}

// Round 19
// 249.225 us; speedup vs baseline: 1.2402x; 1.2402x over previous
//
#include <hip/hip_runtime.h>

#define NN 100000
#define NE 1600000

#define BSHIFT 9
#define NBKT 256            // compile-time max; used = (N+511)>>9 = 196
#define BCAP 12288          // per-bucket staging capacity (avg 8192, sd ~90)
#define TILE 4096

using half8 = __attribute__((ext_vector_type(8))) _Float16;
using f32x4 = __attribute__((ext_vector_type(4))) float;

// ---- bf16 helpers (round-to-nearest-even, matches numpy/jax cast) ----
__device__ inline unsigned short f2bf(float f) {
    unsigned int u = __float_as_uint(f);
    unsigned int r = (u + 0x7fffu + ((u >> 16) & 1u)) >> 16;
    return (unsigned short)r;
}
__device__ inline float bf2f(unsigned short h) {
    return __uint_as_float(((unsigned int)h) << 16);
}
__device__ inline float bflo(unsigned int v) { return __uint_as_float(v << 16); }
__device__ inline float bfhi(unsigned int v) { return __uint_as_float(v & 0xffff0000u); }
__device__ inline unsigned short f2h(float f) {
    union { _Float16 h; unsigned short u; } c; c.h = (_Float16)f; return c.u;
}

// ---- fill pass 1: bucketize edges by dst>>9 into per-bucket staging ----
__global__ __launch_bounds__(256) void k_bucket(
    const int* __restrict__ src, const int* __restrict__ dst,
    int* __restrict__ gcnt, unsigned* __restrict__ stage, int E) {
    __shared__ unsigned st[TILE];
    __shared__ unsigned char stb[TILE];
    __shared__ int hist4[4 * NBKT];
    __shared__ int hist[NBKT];
    __shared__ int s[NBKT];
    __shared__ int offs[NBKT];
    __shared__ int cursor[NBKT];
    __shared__ int gbase[NBKT];
    int tid = threadIdx.x;
    int wv = tid >> 6;
    int t0 = blockIdx.x * TILE;
    int m = E - t0; if (m > TILE) m = TILE;

    for (int i = tid; i < 4 * NBKT; i += 256) hist4[i] = 0;
    __syncthreads();
    for (int i = tid; i < m; i += 256)
        atomicAdd(&hist4[wv * NBKT + (dst[t0 + i] >> BSHIFT)], 1);
    __syncthreads();
    int h = hist4[tid] + hist4[NBKT + tid] + hist4[2 * NBKT + tid] + hist4[3 * NBKT + tid];
    hist[tid] = h;
    s[tid] = h;
    __syncthreads();
    for (int off = 1; off < NBKT; off <<= 1) {
        int t = (tid >= off) ? s[tid - off] : 0;
        __syncthreads();
        s[tid] += t;
        __syncthreads();
    }
    offs[tid] = s[tid] - hist[tid];
    cursor[tid] = s[tid] - hist[tid];
    gbase[tid] = atomicAdd(&gcnt[tid], hist[tid]);
    __syncthreads();
    for (int i = tid; i < m; i += 256) {
        int d = dst[t0 + i];
        int b = d >> BSHIFT;
        unsigned packed = ((unsigned)src[t0 + i] << BSHIFT) | (unsigned)(d & 511);
        int pos = atomicAdd(&cursor[b], 1);
        st[pos] = packed;
        stb[pos] = (unsigned char)b;
    }
    __syncthreads();
    for (int i = tid; i < m; i += 256) {
        int b = stb[i];
        int idx = gbase[b] + (i - offs[b]);
        if (idx < BCAP) stage[(size_t)b * BCAP + idx] = st[i];
    }
}

// ---- degree histogram + dinv + block-local exclusive scan (merged cnt+scan1) ----
__global__ __launch_bounds__(512) void k_cnt_scan(
    const unsigned* __restrict__ stage, const int* __restrict__ gcnt,
    float* __restrict__ dinv, int* __restrict__ row_ptr, int* __restrict__ bsums, int N) {
    __shared__ int h[512];
    __shared__ int s[512];
    int b = blockIdx.x;
    int tid = threadIdx.x;
    h[tid] = 0;
    __syncthreads();
    int n = gcnt[b]; if (n > BCAP) n = BCAP;
    const unsigned* sg = stage + (size_t)b * BCAP;
    for (int i = tid; i < n; i += 512)
        atomicAdd(&h[sg[i] & 511], 1);
    __syncthreads();
    int v = h[tid];
    int d = (b << BSHIFT) | tid;
    if (d < N) dinv[d] = rsqrtf((float)(v + 1));  // +1 self loop
    s[tid] = v;
    __syncthreads();
    for (int off = 1; off < 512; off <<= 1) {
        int t = (tid >= off) ? s[tid - off] : 0;
        __syncthreads();
        s[tid] += t;
        __syncthreads();
    }
    if (d < N) row_ptr[d] = s[tid] - v;   // block-local exclusive
    if (tid == 511) bsums[b] = s[511];
}

// ---- serial scan of bucket sums + row_ptr[N]=E + pooled zero (one tiny block) ----
__global__ void k_scan2(int* __restrict__ bsums, int nb, int* __restrict__ row_ptr,
                        int N, int E, float* __restrict__ pooled) {
    int tid = threadIdx.x;
    if (tid == 0) {
        int run = 0;
        for (int b = 0; b < nb; ++b) { int t = bsums[b]; bsums[b] = run; run += t; }
        row_ptr[N] = E;
    }
    for (int i = tid; i < 64 * 128; i += blockDim.x) pooled[i] = 0.f;
}

// ---- fill pass 2: finalize row_ptr (+bucket offset) and scatter col via LDS cursors ----
__global__ __launch_bounds__(512) void k_scatter(
    const unsigned* __restrict__ stage, const int* __restrict__ gcnt,
    const int* __restrict__ bsums, int* __restrict__ row_ptr,
    int* __restrict__ col, int N) {
    __shared__ int cur[512];
    int b = blockIdx.x;
    int tid = threadIdx.x;
    int add = bsums[b];
    int d0 = (b << BSHIFT) | tid;
    int base = 0;
    if (d0 < N) {
        base = row_ptr[d0] + add;   // block-local excl + bucket offset = global
        row_ptr[d0] = base;         // finalize for k_agg
    }
    cur[tid] = base;
    __syncthreads();
    int n = gcnt[b]; if (n > BCAP) n = BCAP;
    const unsigned* sg = stage + (size_t)b * BCAP;
    for (int i = tid; i < n; i += 512) {
        unsigned e = sg[i];
        int pos = atomicAdd(&cur[e & 511], 1);
        col[pos] = (int)(e >> BSHIFT);
    }
}

// ---- merged prep: x -> bf16 pre-scaled by dinv (first nconv blocks) +
// ---- W1/W2 f32 -> f16 fragment-major packs (12 tail blocks) ----
__global__ void k_prep(const float* __restrict__ x, const float* __restrict__ dinv,
                       unsigned short* __restrict__ xb,
                       const float* __restrict__ W1, const float* __restrict__ W2,
                       half8* __restrict__ w1p, half8* __restrict__ w2p, int n8) {
    int nconv = (n8 + 255) >> 8;
    int bid = blockIdx.x;
    if (bid < nconv) {
        int i = bid * 256 + threadIdx.x;
        if (i >= n8) return;
        float di = dinv[i >> 3];  // 8 floats/thread, 64 ch/row -> row = i/8
        const float4* p = (const float4*)(x + (size_t)i * 8);
        float4 a = p[0], b = p[1];
        uint4 o;
        o.x = (unsigned)f2bf(di * a.x) | ((unsigned)f2bf(di * a.y) << 16);
        o.y = (unsigned)f2bf(di * a.z) | ((unsigned)f2bf(di * a.w) << 16);
        o.z = (unsigned)f2bf(di * b.x) | ((unsigned)f2bf(di * b.y) << 16);
        o.w = (unsigned)f2bf(di * b.z) | ((unsigned)f2bf(di * b.w) << 16);
        ((uint4*)xb)[i] = o;
    } else {
        int t = (bid - nconv) * 256 + threadIdx.x;
        const float* W; half8* wp; int tt;
        if (t < 1024) { W = W1; wp = w1p; tt = t; }
        else if (t < 3072) { W = W2; wp = w2p; tt = t - 1024; }
        else return;
        int s = tt >> 9;
        int j = (tt >> 6) & 7;
        int l = tt & 63;
        half8 hv;
#pragma unroll
        for (int jj = 0; jj < 8; ++jj)
            hv[jj] = (_Float16)W[(size_t)(32 * s + 8 * (l >> 4) + jj) * 128 + 16 * j + (l & 15)];
        wp[tt] = hv;
    }
}

// ------- aggregation: wave/node; rows pre-scaled by dinv[src]; 8 gathers in
// ------- flight, NO serial tail: ceil(m/8) clamped iterations + overcount fixup -------

template <int C>
__global__ void k_agg(const unsigned short* __restrict__ xb, const int* __restrict__ row_ptr,
                      const int* __restrict__ col, const float* __restrict__ dinv,
                      unsigned short* __restrict__ out, int N) {
    int node = blockIdx.x * (blockDim.x >> 6) + (threadIdx.x >> 6);
    int lane = threadIdx.x & 63;
    if (node >= N) return;
    int beg = row_ptr[node], end = row_ptr[node + 1];
    float di = dinv[node];

    if constexpr (C == 64) {
        float acc = bf2f(xb[(size_t)node * 64 + lane]);  // self (pre-scaled by di)
        for (int base = beg; base < end; base += 64) {
            int m = end - base; if (m > 64) m = 64;
            int sel = (lane < m) ? lane : (m - 1);
            int cl = col[base + sel];                    // lanes >= m hold col[base+m-1]
            int iters = (m + 7) & ~7;
            for (int k = 0; k < iters; k += 8) {
                int c0 = __shfl(cl, k),     c1 = __shfl(cl, k + 1);
                int c2 = __shfl(cl, k + 2), c3 = __shfl(cl, k + 3);
                int c4 = __shfl(cl, k + 4), c5 = __shfl(cl, k + 5);
                int c6 = __shfl(cl, k + 6), c7 = __shfl(cl, k + 7);
                unsigned short v0 = xb[(size_t)c0 * 64 + lane];
                unsigned short v1 = xb[(size_t)c1 * 64 + lane];
                unsigned short v2 = xb[(size_t)c2 * 64 + lane];
                unsigned short v3 = xb[(size_t)c3 * 64 + lane];
                unsigned short v4 = xb[(size_t)c4 * 64 + lane];
                unsigned short v5 = xb[(size_t)c5 * 64 + lane];
                unsigned short v6 = xb[(size_t)c6 * 64 + lane];
                unsigned short v7 = xb[(size_t)c7 * 64 + lane];
                acc += bf2f(v0) + bf2f(v1) + bf2f(v2) + bf2f(v3)
                     + bf2f(v4) + bf2f(v5) + bf2f(v6) + bf2f(v7);
            }
            int extra = iters - m;
            if (extra > 0) {
                int clast = __shfl(cl, m - 1);
                acc -= (float)extra * bf2f(xb[(size_t)clast * 64 + lane]);  // L1-hot
            }
        }
        out[(size_t)node * 64 + lane] = f2h(di * acc);
    } else {
        const unsigned int* xb2 = (const unsigned int*)xb;  // 2 bf16 per uint
        unsigned int sv = xb2[(size_t)node * 64 + lane];
        float ax = bflo(sv), ay = bfhi(sv);                 // self (pre-scaled)
        for (int base = beg; base < end; base += 64) {
            int m = end - base; if (m > 64) m = 64;
            int sel = (lane < m) ? lane : (m - 1);
            int cl = col[base + sel];
            int iters = (m + 7) & ~7;
            for (int k = 0; k < iters; k += 8) {
                int c0 = __shfl(cl, k),     c1 = __shfl(cl, k + 1);
                int c2 = __shfl(cl, k + 2), c3 = __shfl(cl, k + 3);
                int c4 = __shfl(cl, k + 4), c5 = __shfl(cl, k + 5);
                int c6 = __shfl(cl, k + 6), c7 = __shfl(cl, k + 7);
                unsigned int v0 = xb2[(size_t)c0 * 64 + lane];
                unsigned int v1 = xb2[(size_t)c1 * 64 + lane];
                unsigned int v2 = xb2[(size_t)c2 * 64 + lane];
                unsigned int v3 = xb2[(size_t)c3 * 64 + lane];
                unsigned int v4 = xb2[(size_t)c4 * 64 + lane];
                unsigned int v5 = xb2[(size_t)c5 * 64 + lane];
                unsigned int v6 = xb2[(size_t)c6 * 64 + lane];
                unsigned int v7 = xb2[(size_t)c7 * 64 + lane];
                ax += bflo(v0) + bflo(v1) + bflo(v2) + bflo(v3)
                    + bflo(v4) + bflo(v5) + bflo(v6) + bflo(v7);
                ay += bfhi(v0) + bfhi(v1) + bfhi(v2) + bfhi(v3)
                    + bfhi(v4) + bfhi(v5) + bfhi(v6) + bfhi(v7);
            }
            int extra = iters - m;
            if (extra > 0) {
                int clast = __shfl(cl, m - 1);
                unsigned int v = xb2[(size_t)clast * 64 + lane];  // L1-hot
                ax -= (float)extra * bflo(v);
                ay -= (float)extra * bfhi(v);
            }
        }
        ((unsigned int*)out)[(size_t)node * 64 + lane] =
            (unsigned int)f2h(di * ax) | ((unsigned int)f2h(di * ay) << 16);
    }
}

// ------- MFMA GEMM (+bias+relu): out[N,128] = A[N,K](f16) @ W[K,128](f16) -------
// SCALE: multiply output row by dinv[row], write bf16 (layer-1 path).
// POOL:  skip the output write; pool via in-register row-sum + shfl_xor
//        cross-lane reduce (NOT per-element atomics - round-18 lesson), with a
//        2-slot LDS accumulator: a 64-row block crosses at most one graph
//        boundary (min graph ~1450 nodes >> 64).

template <int K, bool SCALE, bool POOL>
__global__ __launch_bounds__(256) void k_gemm_mfma(
    const unsigned short* __restrict__ A, const half8* __restrict__ wpack,
    const float* __restrict__ bias, const float* __restrict__ dinv,
    unsigned short* __restrict__ outp, const int* __restrict__ batch,
    float* __restrict__ pooled, int N) {
    __shared__ float pl[2][128];
    int lane = threadIdx.x & 63;
    int wave = threadIdx.x >> 6;
    int row0 = (int)blockIdx.x * 64 + wave * 16;
    int ar = row0 + (lane & 15);
    if (ar >= N) ar = N - 1;
    const _Float16* Ah = (const _Float16*)A;

    int g0 = 0, g1 = 0;
    if constexpr (POOL) {
        for (int i = threadIdx.x; i < 256; i += 256) pl[i >> 7][i & 127] = 0.f;
        int b0 = (int)blockIdx.x * 64;
        int bL = b0 + 63;
        if (b0 > N - 1) b0 = N - 1;
        if (bL > N - 1) bL = N - 1;
        g0 = batch[b0];
        g1 = batch[bL];
        __syncthreads();
    }

    f32x4 acc[8];
#pragma unroll
    for (int j = 0; j < 8; ++j) acc[j] = (f32x4)(0.f);

#pragma unroll
    for (int s = 0; s < K / 32; ++s) {
        half8 av = *(const half8*)(Ah + (size_t)ar * K + 32 * s + 8 * (lane >> 4));
#pragma unroll
        for (int j = 0; j < 8; ++j) {
            half8 bv = wpack[(s * 8 + j) * 64 + lane];
            acc[j] = __builtin_amdgcn_mfma_f32_16x16x32_f16(av, bv, acc[j], 0, 0, 0);
        }
    }

    int rowb = row0 + (lane >> 4) * 4;

    if constexpr (POOL) {
        if (g0 == g1) {
            // uniform-graph block: register row-sum + butterfly over the 4 lanes
            // sharing each column (l, l+16, l+32, l+48) -> 16 LDS adds per wave/j
#pragma unroll
            for (int j = 0; j < 8; ++j) {
                int colc = j * 16 + (lane & 15);
                float b = bias[colc];
                float s = 0.f;
#pragma unroll
                for (int r = 0; r < 4; ++r) {
                    int rr = rowb + r;
                    if (rr < N) s += fmaxf(acc[j][r] + b, 0.f);
                }
                s += __shfl_xor(s, 16);
                s += __shfl_xor(s, 32);
                if (lane < 16) atomicAdd(&pl[0][colc], s);
            }
        } else {
            // boundary block (rare, <=2 graphs): per-element into 2-slot LDS
#pragma unroll
            for (int j = 0; j < 8; ++j) {
                int colc = j * 16 + (lane & 15);
                float b = bias[colc];
#pragma unroll
                for (int r = 0; r < 4; ++r) {
                    int rr = rowb + r;
                    if (rr < N) {
                        float v = fmaxf(acc[j][r] + b, 0.f);
                        int sel = (batch[rr] == g1) ? 1 : 0;
                        atomicAdd(&pl[sel][colc], v);
                    }
                }
            }
        }
        __syncthreads();
        for (int i = threadIdx.x; i < 128; i += 256) {
            float v0 = pl[0][i];
            if (v0 != 0.f) atomicAdd(&pooled[g0 * 128 + i], v0);
            if (g1 != g0) {
                float v1 = pl[1][i];
                if (v1 != 0.f) atomicAdd(&pooled[g1 * 128 + i], v1);
            }
        }
    } else {
        float dv[4];
#pragma unroll
        for (int r = 0; r < 4; ++r) {
            int rr = rowb + r; if (rr >= N) rr = N - 1;
            dv[r] = SCALE ? dinv[rr] : 1.f;
        }
#pragma unroll
        for (int j = 0; j < 8; ++j) {
            int colc = j * 16 + (lane & 15);
            float b = bias[colc];
#pragma unroll
            for (int r = 0; r < 4; ++r) {
                int rr = rowb + r;
                if (rr < N) {
                    float v = fmaxf(acc[j][r] + b, 0.f);
                    if constexpr (SCALE) v *= dv[r];
                    outp[(size_t)rr * 128 + colc] = f2bf(v);
                }
            }
        }
    }
}

// final classify; graph counts via binary search on sorted batch (fused in)
__global__ void k_final(const float* __restrict__ pooled, const int* __restrict__ batch,
                        const float* __restrict__ Wc, const float* __restrict__ bc,
                        float* __restrict__ out, int N) {
    __shared__ int cnts[64];
    int tid = threadIdx.x;
    if (tid < 64) {
        int g = tid;
        int lo = 0, hi = N;
        while (lo < hi) { int mid = (lo + hi) >> 1; if (batch[mid] < g) lo = mid + 1; else hi = mid; }
        int start = lo;
        lo = 0; hi = N;
        while (lo < hi) { int mid = (lo + hi) >> 1; if (batch[mid] < g + 1) lo = mid + 1; else hi = mid; }
        cnts[g] = lo - start;
    }
    __syncthreads();
    for (int idx = tid; idx < 64 * 10; idx += 256) {
        int g = idx / 10, c = idx % 10;
        float s = 0.f;
        for (int k = 0; k < 128; ++k) s += pooled[g * 128 + k] * Wc[k * 10 + c];
        float cnt = (float)cnts[g];
        if (cnt < 1.f) cnt = 1.f;
        out[idx] = s / cnt + bc[c];
    }
}

// ---------------- launch ----------------

extern "C" void kernel_launch(void* const* d_in, const int* in_sizes, int n_in,
                              void* d_out, int out_size, void* d_ws, size_t ws_size,
                              hipStream_t stream) {
    const float* x  = (const float*)d_in[0];
    const float* W1 = (const float*)d_in[1];
    const float* b1 = (const float*)d_in[2];
    const float* W2 = (const float*)d_in[3];
    const float* b2 = (const float*)d_in[4];
    const float* Wc = (const float*)d_in[5];
    const float* bc = (const float*)d_in[6];
    const int* ei   = (const int*)d_in[7];
    const int* batch = (const int*)d_in[8];

    const int E = in_sizes[7] / 2;
    const int N = in_sizes[8];
    const int* src = ei;
    const int* dst = ei + E;

    char* p = (char*)d_ws;
    auto alloc = [&](size_t bytes) -> void* {
        void* r = (void*)p;
        p += (bytes + 255) & ~(size_t)255;
        return r;
    };
    float* dinv     = (float*)alloc((size_t)N * 4);
    int*   row_ptr  = (int*)alloc((size_t)(N + 1) * 4);
    int*   bsums    = (int*)alloc(4096);
    int*   col      = (int*)alloc((size_t)E * 4);
    int*   gcnt     = (int*)alloc(NBKT * 4);
    unsigned* stage = (unsigned*)alloc((size_t)NBKT * BCAP * 4);
    unsigned short* xb    = (unsigned short*)alloc((size_t)N * 64 * 2);   // dinv-scaled x
    unsigned short* h1b   = (unsigned short*)alloc((size_t)N * 128 * 2);  // dinv-scaled h1
    unsigned short* aggb1 = (unsigned short*)alloc((size_t)N * 64 * 2);
    unsigned short* aggb2 = (unsigned short*)alloc((size_t)N * 128 * 2);
    half8* w1p      = (half8*)alloc(1024 * 16);
    half8* w2p      = (half8*)alloc(2048 * 16);
    float* pooled   = (float*)alloc(64 * 128 * 4);

    (void)hipMemsetAsync(gcnt, 0, NBKT * 4, stream);

    int nb = (N + 511) / 512;
    int n8 = N * 8;
    int nconv = (n8 + 255) / 256;

    // bucket edges, then derive degrees / CSR entirely bucket-locally
    k_bucket<<<(E + TILE - 1) / TILE, 256, 0, stream>>>(src, dst, gcnt, stage, E);
    k_cnt_scan<<<nb, 512, 0, stream>>>(stage, gcnt, dinv, row_ptr, bsums, N);
    k_scan2<<<1, 256, 0, stream>>>(bsums, nb, row_ptr, N, E, pooled);
    k_scatter<<<nb, 512, 0, stream>>>(stage, gcnt, bsums, row_ptr, col, N);

    // pre-scaled x + weight packs (single merged launch)
    k_prep<<<nconv + 12, 256, 0, stream>>>(x, dinv, xb, W1, W2, w1p, w2p, n8);

    // layer 1: aggregate scaled x -> f16, MFMA transform -> h1b (bf16, dinv-scaled)
    k_agg<64><<<(N + 3) / 4, 256, 0, stream>>>(xb, row_ptr, col, dinv, aggb1, N);
    k_gemm_mfma<64, true, false><<<(N + 63) / 64, 256, 0, stream>>>(
        aggb1, w1p, b1, dinv, h1b, nullptr, nullptr, N);

    // layer 2: aggregate scaled h1 -> f16, MFMA transform fused with mean-pool
    k_agg<128><<<(N + 3) / 4, 256, 0, stream>>>(h1b, row_ptr, col, dinv, aggb2, N);
    k_gemm_mfma<128, false, true><<<(N + 63) / 64, 256, 0, stream>>>(
        aggb2, w2p, b2, nullptr, nullptr, batch, pooled, N);

    // classify
    k_final<<<1, 256, 0, stream>>>(pooled, batch, Wc, bc, (float*)d_out, N);
}